// Round 21
// baseline (79.934 us; speedup 1.0000x reference)
//
#include <hip/hip_runtime.h>
#include <hip/hip_bf16.h>

#define D_ 64
#define HW_ 4096
#define K_ 1024
#define NPTS_ 65536
#define QOUT_ 4194304      // B*D*H*W, offset of idx region in d_out
#define DELTA 0.006f       // ambiguity margin; worst-case bf16-split diff ~2e-3
#define INF_ 3.4e38f
#define NCH 32             // chunks of 32 codes (8 KB each)

typedef short bf16x8 __attribute__((ext_vector_type(8)));
typedef float f32x4 __attribute__((ext_vector_type(4)));

__device__ __forceinline__ void gload_lds16(const float* g, float* l) {
    __builtin_amdgcn_global_load_lds((const __attribute__((address_space(1))) void*)g,
                                     (__attribute__((address_space(3))) void*)l, 16, 0, 0);
}

// ---- pack kernel: cnorm + bf16 hi/lo split of (-2*cb) in MFMA-fragment order ----
// P layout (shorts): [gch(64)][frag(4)][lane(64)][8]
//   code j = gch*16 + (l&15), dims d = (frag>>1)*32 + (l>>4)*8 + i, lvl = frag&1
__global__ __launch_bounds__(64) void vq_pack(const float* __restrict__ cb,
                                              float* __restrict__ cnorm,
                                              short* __restrict__ P) {
    const int t = blockIdx.x * 64 + threadIdx.x;    // 0..4095, 64 blocks
    const int gch = t >> 6, l = t & 63;
    const int j  = gch * 16 + (l & 15);
    const int dg = l >> 4;
#pragma unroll
    for (int s = 0; s < 2; ++s) {
        const float* src = cb + j * D_ + s * 32 + dg * 8;
        short hb[8], lb[8];
#pragma unroll
        for (int i = 0; i < 8; ++i) {
            const float v = -2.f * src[i];
            __hip_bfloat16 h = __float2bfloat16(v);
            hb[i] = *(const short*)&h;
            const float r = v - __bfloat162float(h);
            __hip_bfloat16 lo = __float2bfloat16(r);
            lb[i] = *(const short*)&lo;
        }
        short* dh = P + ((size_t)(gch * 4 + s * 2 + 0) * 64 + l) * 8;
        short* dl = P + ((size_t)(gch * 4 + s * 2 + 1) * 64 + l) * 8;
#pragma unroll
        for (int i = 0; i < 8; ++i) { dh[i] = hb[i]; dl[i] = lb[i]; }
    }
    if (t < K_) {
        const float4* r = (const float4*)(cb + (size_t)t * D_);
        float s0 = 0.f, s1 = 0.f, s2 = 0.f, s3 = 0.f;
#pragma unroll
        for (int i = 0; i < 16; ++i) {
            float4 v = r[i];
            s0 = fmaf(v.x, v.x, s0); s1 = fmaf(v.y, v.y, s1);
            s2 = fmaf(v.z, v.z, s2); s3 = fmaf(v.w, v.w, s3);
        }
        cnorm[t] = (s0 + s1) + (s2 + s3);
    }
}

// ---- main: R12's proven 43.5us search structure + fused rescan, idx only ----
// 1024 blocks x 256 thr (4 waves x 16 pts = 64 pts). 32-code chunks,
// double-buffered (2x8KB), plain __syncthreads per chunk. Writes FINAL clean
// idx; quantized write moved to element-parallel vq_write (R20 lesson: fused
// gather/transpose costs ~25us at 2-4 blocks/CU vs ~7us at 16 blocks/CU).
__global__ __launch_bounds__(256, 4) void vq_main(const float* __restrict__ x,
                                                  const float* __restrict__ cb,
                                                  const float* __restrict__ cnorm_g,
                                                  const short* __restrict__ P,
                                                  float* __restrict__ out) {
    __shared__ short cbuf[2][4096];   // 2 x 8 KB: 32 codes per buffer
    __shared__ float cnt[K_];         // 4 KB
    __shared__ int res_idx[64];
    __shared__ int flist[64];
    __shared__ int fcnt;

    const int tid  = threadIdx.x;
    const int lane = tid & 63;
    const int wid  = tid >> 6;        // 0..3
    const int pg   = blockIdx.x;      // 0..1023
    const int bb   = pg >> 6;
    const int hw0  = (pg & 63) << 6;

    if (tid == 0) fcnt = 0;

    const float* Pf = (const float*)P;

    // stage cnorm (4 KB) + chunk 0 (8 KB)
    gload_lds16(cnorm_g + wid * 256 + lane * 4, cnt + wid * 256);
#pragma unroll
    for (int r = 0; r < 2; ++r)
        gload_lds16(Pf + (wid * 2 + r) * 256 + lane * 4,
                    (float*)cbuf[0] + (wid * 2 + r) * 256);

    // load + split x fragment: wave owns 16 points, lane holds point (l&15)
    bf16x8 ah[2], al[2];
    {
        const float* xb = x + (size_t)bb * (D_ * HW_) + hw0;
        const int p_l = wid * 16 + (lane & 15);
#pragma unroll
        for (int s = 0; s < 2; ++s) {
            const int d0 = s * 32 + (lane >> 4) * 8;
#pragma unroll
            for (int i = 0; i < 8; ++i) {
                const float v = xb[(size_t)(d0 + i) * HW_ + p_l];
                __hip_bfloat16 h = __float2bfloat16(v);
                ah[s][i] = *(const short*)&h;
                const float r = v - __bfloat162float(h);
                __hip_bfloat16 lo = __float2bfloat16(r);
                al[s][i] = *(const short*)&lo;
            }
        }
    }
    asm volatile("s_waitcnt vmcnt(0)" ::: "memory");
    __syncthreads();

    float m1[4], m2[4];
    int   i1[4];
#pragma unroll
    for (int q = 0; q < 4; ++q) { m1[q] = INF_; m2[q] = INF_; i1[q] = 0; }

    int cur = 0;
#pragma unroll 1
    for (int c = 0; c < NCH; ++c) {
        // prefetch next chunk first: lands under this chunk's compute
        if (c + 1 < NCH) {
            const float* src = Pf + (size_t)(c + 1) * 2048;
            float* dst = (float*)cbuf[cur ^ 1];
#pragma unroll
            for (int r = 0; r < 2; ++r)
                gload_lds16(src + (wid * 2 + r) * 256 + lane * 4,
                            dst + (wid * 2 + r) * 256);
        }
        const bf16x8* fr = (const bf16x8*)cbuf[cur];
#pragma unroll
        for (int u = 0; u < 2; ++u) {
            const int kc = c * 32 + u * 16 + (lane & 15);
            const float cn = cnt[kc];
            bf16x8 bh0 = fr[(u * 4 + 0) * 64 + lane];
            bf16x8 bl0 = fr[(u * 4 + 1) * 64 + lane];
            bf16x8 bh1 = fr[(u * 4 + 2) * 64 + lane];
            bf16x8 bl1 = fr[(u * 4 + 3) * 64 + lane];
            f32x4 aa = {0.f, 0.f, 0.f, 0.f};   // dims 0-31 (3-deep chain)
            f32x4 ab = {0.f, 0.f, 0.f, 0.f};   // dims 32-63 (3-deep chain)
            aa = __builtin_amdgcn_mfma_f32_16x16x32_bf16(ah[0], bh0, aa, 0, 0, 0);
            ab = __builtin_amdgcn_mfma_f32_16x16x32_bf16(ah[1], bh1, ab, 0, 0, 0);
            aa = __builtin_amdgcn_mfma_f32_16x16x32_bf16(al[0], bh0, aa, 0, 0, 0);
            ab = __builtin_amdgcn_mfma_f32_16x16x32_bf16(al[1], bh1, ab, 0, 0, 0);
            aa = __builtin_amdgcn_mfma_f32_16x16x32_bf16(ah[0], bl0, aa, 0, 0, 0);
            ab = __builtin_amdgcn_mfma_f32_16x16x32_bf16(ah[1], bl1, ab, 0, 0, 0);
#pragma unroll
            for (int r = 0; r < 4; ++r) {
                const float d2 = cn + (aa[r] + ab[r]);
                const bool lt = d2 < m1[r];
                m2[r] = fminf(m2[r], fmaxf(m1[r], d2));  // min(m2, loser)
                m1[r] = fminf(m1[r], d2);
                i1[r] = lt ? kc : i1[r];
            }
        }
        __syncthreads();   // prefetch complete + all waves done reading cur
        cur ^= 1;
    }

    // cross-lane (m1,i1,m2) reduce over the 16 lanes sharing (lane>>4)
#pragma unroll
    for (int q = 0; q < 4; ++q) {
        float a1 = m1[q], a2 = m2[q];
        int   ai = i1[q];
#pragma unroll
        for (int m = 1; m < 16; m <<= 1) {
            const float o1 = __shfl_xor(a1, m);
            const int   oi = __shfl_xor(ai, m);
            const float o2 = __shfl_xor(a2, m);
            const float nm2 = fminf(fminf(a2, o2), fmaxf(a1, o1));
            if (o1 < a1 || (o1 == a1 && oi < ai)) { a1 = o1; ai = oi; }
            a2 = nm2;
        }
        if ((lane & 15) == 0) {
            const int pt = wid * 16 + 4 * (lane >> 4) + q;
            res_idx[pt] = ai;
            if (a2 - a1 <= DELTA) { const int p = atomicAdd(&fcnt, 1); flist[p] = pt; }
        }
    }
    __syncthreads();

    // exact fp32 rescan for ambiguous points (expected ~0.05/block)
    const int nf = fcnt;
    for (int i = wid; i < nf; i += 4) {
        const int pt = flist[i];
        const float* xr = x + (size_t)bb * (D_ * HW_) + hw0 + pt;
        float xv[D_];
#pragma unroll
        for (int d = 0; d < D_; ++d) xv[d] = xr[(size_t)d * HW_];   // wave-uniform
        float b1 = INF_; int bi = 0;
        for (int cc = 0; cc < 16; ++cc) {
            const int row = lane * 16 + cc;
            const float4* cr = (const float4*)(cb + (size_t)row * D_);
            float a0 = 0.f, a1 = 0.f, a2 = 0.f, a3 = 0.f;
#pragma unroll
            for (int g = 0; g < 16; ++g) {
                const float4 cf = cr[g];
                a0 = fmaf(xv[4 * g + 0], cf.x, a0);
                a1 = fmaf(xv[4 * g + 1], cf.y, a1);
                a2 = fmaf(xv[4 * g + 2], cf.z, a2);
                a3 = fmaf(xv[4 * g + 3], cf.w, a3);
            }
            const float dot = (a0 + a1) + (a2 + a3);
            const float d2 = fmaf(-2.f, dot, cnt[row]);
            if (d2 < b1) { b1 = d2; bi = row; }
        }
#pragma unroll
        for (int m = 1; m < 64; m <<= 1) {
            const float o1 = __shfl_xor(b1, m);
            const int   oi = __shfl_xor(bi, m);
            if (o1 < b1 || (o1 == b1 && oi < bi)) { b1 = o1; bi = oi; }
        }
        if (lane == 0) res_idx[pt] = bi;
    }
    __syncthreads();

    // FINAL clean idx output (float; exact for values <= 1023)
    if (tid < 64) out[(size_t)QOUT_ + (pg << 6) + tid] = (float)res_idx[tid];
}

// ---- write: element-parallel gather of quantized output ----
// One thread per output float4. 4096 blocks -> 16 blocks/CU (TLP hides gather
// latency). idx read: coalesced float4. cb gathers: L2-resident (256 KB).
// Stores: 64 lanes x 16 B = 1 KB contiguous per instruction.
__global__ __launch_bounds__(256) void vq_write(const float* __restrict__ cb,
                                                float* __restrict__ out) {
    const int e = blockIdx.x * 256 + threadIdx.x;    // 0..1048575
    const int b = e >> 16;
    const int r = e & 65535;
    const int d = r >> 10;
    const int g = r & 1023;
    const float4 fi = *(const float4*)(out + (size_t)QOUT_ + b * HW_ + g * 4);
    float4 q;
    q.x = cb[(size_t)((int)fi.x) * D_ + d];
    q.y = cb[(size_t)((int)fi.y) * D_ + d];
    q.z = cb[(size_t)((int)fi.z) * D_ + d];
    q.w = cb[(size_t)((int)fi.w) * D_ + d];
    *(float4*)(out + ((size_t)b * D_ + d) * HW_ + g * 4) = q;
}

extern "C" void kernel_launch(void* const* d_in, const int* in_sizes, int n_in,
                              void* d_out, int out_size, void* d_ws, size_t ws_size,
                              hipStream_t stream) {
    const float* x  = (const float*)d_in[0];   // (16, 64, 64, 64)
    const float* cb = (const float*)d_in[1];   // (1024, 64)
    float* out   = (float*)d_out;
    float* cnorm = (float*)d_ws;                       // 4 KB
    short* P     = (short*)((char*)d_ws + 4096);       // 256 KB packed bf16 codebook

    vq_pack<<<64, 64, 0, stream>>>(cb, cnorm, P);
    vq_main<<<NPTS_ / 64, 256, 0, stream>>>(x, cb, cnorm, P, out);
    vq_write<<<(NPTS_ * D_ / 4) / 256, 256, 0, stream>>>(cb, out);
}